// Round 13
// baseline (233.358 us; speedup 1.0000x reference)
//
#include <hip/hip_runtime.h>
#include <math.h>
#include <stdlib.h>

#define B 4
#define N 1024
#define D 64
#define H 8
#define DH 64
#define INNER 512
#define C3 1536
#define BHN 32768        // B*H*N
#define BHND 2097152     // B*H*N*DH

typedef __attribute__((ext_vector_type(8))) short bf16x8;
typedef __attribute__((ext_vector_type(4))) float f32x4;

__device__ inline short f2bf(float f) {
    unsigned u = __builtin_bit_cast(unsigned, f);
    unsigned r = (u + 0x7FFFu + ((u >> 16) & 1u)) >> 16;
    return (short)r;
}
__device__ inline float bf2f(short s) {
    return __builtin_bit_cast(float, ((unsigned)(unsigned short)s) << 16);
}

// ---------------- prep: x->xh/xl+sq | Wqkv->Wh/Wl transposed | spa | scal zero ----------------
__global__ __launch_bounds__(256) void k_prep(const float* __restrict__ x, const float* __restrict__ Wqkv,
                                              short* __restrict__ xh, short* __restrict__ xl,
                                              float* __restrict__ sq,
                                              short* __restrict__ Wh, short* __restrict__ Wl,
                                              float* __restrict__ spa, float inv2s2, float mu,
                                              float* __restrict__ scal) {
    __shared__ float lds[64 * 65];
    int t = threadIdx.x;
    int bb = blockIdx.x;
    if (bb < 1024) {
        if (bb == 0 && t < 16) scal[t] = 0.f;
        int i = bb * 4 + (t >> 6), d = t & 63;
        float v = x[i * 64 + d];
        short hs = f2bf(v);
        xh[i * 64 + d] = hs;
        xl[i * 64 + d] = f2bf(v - bf2f(hs));
        float s = v * v;
#pragma unroll
        for (int m = 32; m; m >>= 1) s += __shfl_xor(s, m, 64);
        if (d == 0) sq[i] = s;
    } else if (bb < 1048) {
        int c0 = (bb - 1024) * 64;
#pragma unroll
        for (int it = 0; it < 16; it++) {
            int d = it * 4 + (t >> 6), cl = t & 63;
            lds[cl * 65 + d] = Wqkv[d * C3 + c0 + cl];
        }
        __syncthreads();
#pragma unroll
        for (int it = 0; it < 16; it++) {
            int cl = it * 4 + (t >> 6), d = t & 63;
            float v = lds[cl * 65 + d];
            short hs = f2bf(v);
            Wh[(c0 + cl) * 64 + d] = hs;
            Wl[(c0 + cl) * 64 + d] = f2bf(v - bf2f(hs));
        }
    } else {
        int flat4 = (bb - 1048) * 256 + t;
        int i = flat4 >> 8;
        int j0 = (flat4 & 255) * 4;
        int ix = i >> 6, iy = (i >> 2) & 15, iz = i & 3;
        float4 o;
        float* op = (float*)&o;
#pragma unroll
        for (int jj = 0; jj < 4; jj++) {
            int j = j0 + jj;
            int jx = j >> 6, jy = (j >> 2) & 15, jz = j & 3;
            float d2 = (float)((ix - jx) * (ix - jx) + (iy - jy) * (iy - jy) + (iz - jz) * (iz - jz));
            float w = __expf(-d2 * inv2s2);
            op[jj] = (w < mu) ? 0.f : w;
        }
        ((float4*)spa)[flat4] = o;
    }
}

// ---------------- fused GEMM kernel: qkv-proj (blocks <768) | gram (blocks >=768) ----------------
__global__ __launch_bounds__(256) void k_gemm(
    const short* __restrict__ xh, const short* __restrict__ xl,
    const short* __restrict__ Wh, const short* __restrict__ Wl,
    const float* __restrict__ bqkv, const float* __restrict__ sq,
    short* __restrict__ qeh, short* __restrict__ qel,
    short* __restrict__ keh,
    short* __restrict__ vT, float* __restrict__ w, float* __restrict__ d_sig) {
    __shared__ short vt_lds[128 * 66];
    __shared__ float red[4];
    int t = threadIdx.x;
    int wv = t >> 6, lane = t & 63, l4 = lane & 15, g = lane >> 4;
    const bf16x8* xh8 = (const bf16x8*)xh;
    const bf16x8* xl8 = (const bf16x8*)xl;

    if (blockIdx.x < 768) {
        int i0 = (blockIdx.x & 63) * 64;
        int c0 = (blockIdx.x >> 6) * 128;
        int irow = i0 + wv * 16;
        const bf16x8* Wh8 = (const bf16x8*)Wh;
        const bf16x8* Wl8 = (const bf16x8*)Wl;
        int abase = (irow + l4) * 8 + g;
        bf16x8 ah[2], al[2];
        ah[0] = xh8[abase];
        ah[1] = xh8[abase + 4];
        al[0] = xl8[abase];
        al[1] = xl8[abase + 4];
        f32x4 acc[8];
#pragma unroll
        for (int ct = 0; ct < 8; ct++) {
            int c = c0 + 16 * ct + l4;
            int bbase = c * 8 + g;
            bf16x8 bh0 = Wh8[bbase], bh1 = Wh8[bbase + 4];
            bf16x8 bl0 = Wl8[bbase], bl1 = Wl8[bbase + 4];
            f32x4 a = f32x4{0.f, 0.f, 0.f, 0.f};
            a = __builtin_amdgcn_mfma_f32_16x16x32_bf16(ah[0], bh0, a, 0, 0, 0);
            a = __builtin_amdgcn_mfma_f32_16x16x32_bf16(ah[1], bh1, a, 0, 0, 0);
            a = __builtin_amdgcn_mfma_f32_16x16x32_bf16(al[0], bh0, a, 0, 0, 0);
            a = __builtin_amdgcn_mfma_f32_16x16x32_bf16(al[1], bh1, a, 0, 0, 0);
            a = __builtin_amdgcn_mfma_f32_16x16x32_bf16(ah[0], bl0, a, 0, 0, 0);
            a = __builtin_amdgcn_mfma_f32_16x16x32_bf16(ah[1], bl1, a, 0, 0, 0);
            acc[ct] = a;
        }
        int seg = c0 >> 9;
#pragma unroll
        for (int ct = 0; ct < 8; ct++) {
            int c = c0 + 16 * ct + l4;
            float bias = bqkv[c];
            int cc = c & 511, hh = cc >> 6, dh = cc & 63;
#pragma unroll
            for (int r = 0; r < 4; r++) {
                int i_e = irow + 4 * g + r;
                int b = i_e >> 10, i = i_e & 1023;
                float val = acc[ct][r] + bias;
                if (seg < 2) {
                    float a_ = val > 0.f ? val + 1.f : __expf(val);
                    short hs = f2bf(a_);
                    int off = ((b * H + hh) * N + i) * 64 + dh;
                    if (seg == 0) {
                        qeh[off] = hs;
                        qel[off] = f2bf(a_ - bf2f(hs));
                    } else {
                        keh[off] = hs;
                    }
                } else {
                    vt_lds[(16 * ct + l4) * 66 + (wv * 16 + 4 * g + r)] = f2bf(val);
                }
            }
        }
        if (seg == 2) {
            __syncthreads();
            int b = i0 >> 10, ib = i0 & 1023;
#pragma unroll
            for (int it = 0; it < 4; it++) {
                int idx = t + 256 * it;
                int cl = idx >> 3, i8 = idx & 7;
                short tmp[8];
#pragma unroll
                for (int r8 = 0; r8 < 8; r8++) tmp[r8] = vt_lds[cl * 66 + i8 * 8 + r8];
                int cc = (c0 + cl) & 511, hh = cc >> 6, dh = cc & 63;
                ((bf16x8*)vT)[((b * H + hh) * 64 + dh) * (N / 8) + (ib >> 3) + i8] = *(bf16x8*)tmp;
            }
        }
    } else {
        int q = blockIdx.x - 768;
        int i0 = (q & 15) * 64, j0 = ((q >> 4) & 7) * 128, b = q >> 7;
        int irow = i0 + wv * 16;
        int abase = (b * N + irow + l4) * 8 + g;
        bf16x8 ah[2], al[2];
        ah[0] = xh8[abase];
        ah[1] = xh8[abase + 4];
        al[0] = xl8[abase];
        al[1] = xl8[abase + 4];
        f32x4 acc[8];
#pragma unroll
        for (int ct = 0; ct < 8; ct++) {
            int j = j0 + 16 * ct + l4;
            int bbase = (b * N + j) * 8 + g;
            bf16x8 bh0 = xh8[bbase], bh1 = xh8[bbase + 4];
            bf16x8 bl0 = xl8[bbase], bl1 = xl8[bbase + 4];
            f32x4 a = f32x4{0.f, 0.f, 0.f, 0.f};
            a = __builtin_amdgcn_mfma_f32_16x16x32_bf16(ah[0], bh0, a, 0, 0, 0);
            a = __builtin_amdgcn_mfma_f32_16x16x32_bf16(ah[1], bh1, a, 0, 0, 0);
            a = __builtin_amdgcn_mfma_f32_16x16x32_bf16(al[0], bh0, a, 0, 0, 0);
            a = __builtin_amdgcn_mfma_f32_16x16x32_bf16(al[1], bh1, a, 0, 0, 0);
            a = __builtin_amdgcn_mfma_f32_16x16x32_bf16(ah[0], bl0, a, 0, 0, 0);
            a = __builtin_amdgcn_mfma_f32_16x16x32_bf16(ah[1], bl1, a, 0, 0, 0);
            acc[ct] = a;
        }
        float sqi[4];
#pragma unroll
        for (int r = 0; r < 4; r++) sqi[r] = sq[b * N + irow + 4 * g + r];
        float part = 0.f;
#pragma unroll
        for (int ct = 0; ct < 8; ct++) {
            int j = j0 + 16 * ct + l4;
            float sqj = sq[b * N + j];
#pragma unroll
            for (int r = 0; r < 4; r++) {
                float d2 = sqi[r] + sqj - 2.f * acc[ct][r];
                d2 = fmaxf(d2, 0.f);
                w[((size_t)b * N + irow + 4 * g + r) * N + j] = d2;
                part += (d2 > 1e-12f) ? sqrtf(d2) : 0.f;
            }
        }
#pragma unroll
        for (int m = 32; m; m >>= 1) part += __shfl_xor(part, m, 64);
        if (lane == 0) red[wv] = part;
        __syncthreads();
        if (t == 0) atomicAdd(d_sig, red[0] + red[1] + red[2] + red[3]);
    }
}

// ---------------- wsum: read-only reduction of exp(-d2/(2 sigma^2)) ----------------
__global__ __launch_bounds__(256) void k_wsum(const float* __restrict__ w, const float* __restrict__ d_sig,
                                              float* __restrict__ d_wsum) {
    __shared__ float red[4];
    float sigma = d_sig[0] * (1.f / 4194304.f);
    float inv = 1.f / (2.f * sigma * sigma);
    float s = 0.f;
    for (int idx = blockIdx.x * 256 + threadIdx.x; idx < 1048576; idx += 256 * 2048) {
        float4 v = ((const float4*)w)[idx];
        s += __expf(-v.x * inv) + __expf(-v.y * inv) + __expf(-v.z * inv) + __expf(-v.w * inv);
    }
#pragma unroll
    for (int m = 32; m; m >>= 1) s += __shfl_xor(s, m, 64);
    if ((threadIdx.x & 63) == 0) red[threadIdx.x >> 6] = s;
    __syncthreads();
    if (threadIdx.x == 0) atomicAdd(d_wsum, red[0] + red[1] + red[2] + red[3]);
}

// ---------------- mask: Mb = thresh(exp(-d2 inv))*spa*0.125 in bf16 ----------------
__global__ __launch_bounds__(256) void k_mask(const float* __restrict__ w, const float* __restrict__ spa,
                                              const float* __restrict__ scal, short* __restrict__ Mb) {
    float sigma = scal[0] * (1.f / 4194304.f);
    float inv = 1.f / (2.f * sigma * sigma);
    float mu = scal[1] * (1.f / 4194304.f);
    float d2thr = -__logf(mu) / inv;   // w < mu  <=>  d2 > d2thr
    for (int idx = blockIdx.x * 256 + threadIdx.x; idx < 1048576; idx += 256 * 2048) {
        float4 d2v = ((const float4*)w)[idx];
        float4 sp = ((const float4*)spa)[idx & 262143];
        short tmp[4];
        float* dp = (float*)&d2v;
        float* pp = (float*)&sp;
#pragma unroll
        for (int e = 0; e < 4; e++) {
            float m = (dp[e] > d2thr) ? 0.f : __expf(-dp[e] * inv) * pp[e] * 0.125f;
            tmp[e] = f2bf(m);
        }
        *(uint2*)(Mb + (size_t)idx * 4) = *(uint2*)tmp;
    }
}

// ---------------- attention: MFMA flash, bf16 mask, dbuf K/V, async stage, XCD-grouped ----------------
__global__ __launch_bounds__(256) void k_attn(
    const short* __restrict__ qeh, const short* __restrict__ qel,
    const short* __restrict__ keh,
    const short* __restrict__ vT, const short* __restrict__ Mb,
    float* __restrict__ aout) {
    __shared__ short Kh[2][64 * 64];
    __shared__ short Vt[2][64 * 64];
    __shared__ short P[4][16 * 64];
    int t = threadIdx.x;
    int wv = t >> 6, lane = t & 63, l4 = lane & 15, g = lane >> 4;
    // XCD-grouped decode: consecutive bid round-robin XCDs; same (b,h) shares bid%8
    int bid = blockIdx.x;
    int h = bid & 7;
    int iblk = (bid >> 3) & 15;
    int b = bid >> 7;
    int i0 = iblk * 64;
    int bh = b * H + h;
    int irow = i0 + wv * 16;

    bf16x8 qh[2], ql[2];
    {
        const bf16x8* qh8 = (const bf16x8*)qeh;
        const bf16x8* ql8 = (const bf16x8*)qel;
        int base = (bh * N + irow + l4) * 8 + g;
#pragma unroll
        for (int mk = 0; mk < 2; mk++) {
            qh[mk] = qh8[base + 4 * mk];
            ql[mk] = ql8[base + 4 * mk];
        }
    }
    f32x4 O[4];
#pragma unroll
    for (int dt = 0; dt < 4; dt++) O[dt] = f32x4{0.f, 0.f, 0.f, 0.f};
    float m_r[4] = {-INFINITY, -INFINITY, -INFINITY, -INFINITY};
    float l_r[4] = {0.f, 0.f, 0.f, 0.f};

    const bf16x8* kh8 = (const bf16x8*)keh;
    const bf16x8* v8 = (const bf16x8*)vT;
    int j_a = (t + 0) >> 3, s_a = (t + 0) & 7;        // chunk rep 0
    int j_b = (t + 256) >> 3, s_b = (t + 256) & 7;    // chunk rep 1

    bf16x8 rk[2], rv[2];
    // LOAD(tile): issue global loads for tile into regs
#define LOAD_T(T)                                                            \
    {                                                                        \
        int j0_ = (T) * 64;                                                  \
        rk[0] = kh8[(bh * N + j0_ + j_a) * 8 + s_a];                         \
        rk[1] = kh8[(bh * N + j0_ + j_b) * 8 + s_b];                         \
        rv[0] = v8[(bh * 64 + j_a) * (N / 8) + (j0_ >> 3) + s_a];            \
        rv[1] = v8[(bh * 64 + j_b) * (N / 8) + (j0_ >> 3) + s_b];            \
    }
#define STORE_T(BUF)                                                         \
    {                                                                        \
        ((bf16x8*)Kh[BUF])[j_a * 8 + (s_a ^ (j_a & 7))] = rk[0];             \
        ((bf16x8*)Kh[BUF])[j_b * 8 + (s_b ^ (j_b & 7))] = rk[1];             \
        ((bf16x8*)Vt[BUF])[j_a * 8 + (s_a ^ (j_a & 7))] = rv[0];             \
        ((bf16x8*)Vt[BUF])[j_b * 8 + (s_b ^ (j_b & 7))] = rv[1];             \
    }

    LOAD_T(0);
    STORE_T(0);
    LOAD_T(1);
    __syncthreads();

    for (int tile = 0; tile < 16; ++tile) {
        int cur = tile & 1, nxt = cur ^ 1;
        int j0 = tile * 64;
        if (tile < 15) STORE_T(nxt);     // write tile+1 regs (safe: prev-iter barrier passed)
        if (tile < 14) LOAD_T(tile + 2); // issue tile+2 loads early (latency hides under compute)

        const bf16x8* Kh8 = (const bf16x8*)Kh[cur];
        const bf16x8* Vt8 = (const bf16x8*)Vt[cur];
        f32x4 sc[4];
        __builtin_amdgcn_s_setprio(1);
#pragma unroll
        for (int ct = 0; ct < 4; ct++) {
            int j = 16 * ct + l4;
            int sw = j & 7;
            bf16x8 kh0 = Kh8[j * 8 + ((g) ^ sw)];
            bf16x8 kh1 = Kh8[j * 8 + ((4 + g) ^ sw)];
            f32x4 a = f32x4{0.f, 0.f, 0.f, 0.f};
            a = __builtin_amdgcn_mfma_f32_16x16x32_bf16(qh[0], kh0, a, 0, 0, 0);
            a = __builtin_amdgcn_mfma_f32_16x16x32_bf16(qh[1], kh1, a, 0, 0, 0);
            a = __builtin_amdgcn_mfma_f32_16x16x32_bf16(ql[0], kh0, a, 0, 0, 0);
            a = __builtin_amdgcn_mfma_f32_16x16x32_bf16(ql[1], kh1, a, 0, 0, 0);
            sc[ct] = a;
        }
        __builtin_amdgcn_s_setprio(0);
        float p[4][4];
        float fr[4];
#pragma unroll
        for (int r = 0; r < 4; r++) {
            int i = irow + 4 * g + r;
            const short* Mrow = Mb + ((size_t)b * N + i) * N + j0;
            float mx = -INFINITY;
#pragma unroll
            for (int ct = 0; ct < 4; ct++) {
                float mval = bf2f(Mrow[16 * ct + l4]);
                float val = sc[ct][r] * mval;
                p[ct][r] = val;
                mx = fmaxf(mx, val);
            }
#pragma unroll
            for (int msk = 1; msk < 16; msk <<= 1) mx = fmaxf(mx, __shfl_xor(mx, msk, 64));
            float mo = m_r[r];
            float mn = fmaxf(mo, mx);
            float f = __expf(mo - mn);
            float s = 0.f;
#pragma unroll
            for (int ct = 0; ct < 4; ct++) {
                float e = __expf(p[ct][r] - mn);
                p[ct][r] = e;
                s += e;
            }
#pragma unroll
            for (int msk = 1; msk < 16; msk <<= 1) s += __shfl_xor(s, msk, 64);
            l_r[r] = l_r[r] * f + s;
            m_r[r] = mn;
            fr[r] = f;
        }
#pragma unroll
        for (int dt = 0; dt < 4; dt++) {
            O[dt][0] *= fr[0];
            O[dt][1] *= fr[1];
            O[dt][2] *= fr[2];
            O[dt][3] *= fr[3];
        }
        short* Pw = P[wv];
#pragma unroll
        for (int ct = 0; ct < 4; ct++) {
#pragma unroll
            for (int r = 0; r < 4; r++) {
                int row = 4 * g + r;
                int slot = ((l4 >> 3) + 2 * ct) ^ (row & 7);
                Pw[row * 64 + slot * 8 + (l4 & 7)] = f2bf(p[ct][r]);
            }
        }
        const bf16x8* Pr = (const bf16x8*)P[wv];
        __builtin_amdgcn_s_setprio(1);
#pragma unroll
        for (int ks = 0; ks < 2; ks++) {
            bf16x8 pa = Pr[l4 * 8 + ((g + 4 * ks) ^ (l4 & 7))];
#pragma unroll
            for (int dt = 0; dt < 4; dt++) {
                int d = l4 + 16 * dt;
                bf16x8 bv = Vt8[d * 8 + ((g + 4 * ks) ^ (d & 7))];
                O[dt] = __builtin_amdgcn_mfma_f32_16x16x32_bf16(pa, bv, O[dt], 0, 0, 0);
            }
        }
        __builtin_amdgcn_s_setprio(0);
        __syncthreads();
    }
#pragma unroll
    for (int dt = 0; dt < 4; dt++) {
#pragma unroll
        for (int r = 0; r < 4; r++) {
            int i = irow + 4 * g + r;
            aout[((size_t)b * N + i) * INNER + h * 64 + l4 + 16 * dt] = O[dt][r] / l_r[r];
        }
    }
#undef LOAD_T
#undef STORE_T
}

// ---------------- LN + GELU + out proj (8 rows/block) ----------------
__global__ __launch_bounds__(256) void k_out(const float* __restrict__ aout, const float* __restrict__ g,
                                             const float* __restrict__ be, const float* __restrict__ Wout,
                                             const float* __restrict__ bout, float* __restrict__ out) {
    __shared__ float y_s[8 * 512];
    int t = threadIdx.x;
    int wv = t >> 6, lane = t & 63;
    int r0 = blockIdx.x * 8;
#pragma unroll
    for (int rr = 0; rr < 2; rr++) {
        int rloc = wv * 2 + rr;
        const float* rp = aout + (size_t)(r0 + rloc) * 512;
        float4 v0 = ((const float4*)rp)[lane];
        float4 v1 = ((const float4*)rp)[lane + 64];
        float s1 = v0.x + v0.y + v0.z + v0.w + v1.x + v1.y + v1.z + v1.w;
        float s2 = v0.x * v0.x + v0.y * v0.y + v0.z * v0.z + v0.w * v0.w +
                   v1.x * v1.x + v1.y * v1.y + v1.z * v1.z + v1.w * v1.w;
#pragma unroll
        for (int m = 32; m; m >>= 1) {
            s1 += __shfl_xor(s1, m, 64);
            s2 += __shfl_xor(s2, m, 64);
        }
        float mean = s1 * (1.f / 512.f);
        float var = s2 * (1.f / 512.f) - mean * mean;
        float rstd = rsqrtf(var + 1e-5f);
        int c0 = 4 * lane, c1 = 4 * lane + 256;
        float4 o0, o1;
#pragma unroll
        for (int e = 0; e < 4; e++) {
            float yn = g[c0 + e] * (((float*)&v0)[e] - mean) * rstd + be[c0 + e];
            ((float*)&o0)[e] = 0.5f * yn * (1.f + erff(yn * 0.70710678118f));
            float ym = g[c1 + e] * (((float*)&v1)[e] - mean) * rstd + be[c1 + e];
            ((float*)&o1)[e] = 0.5f * ym * (1.f + erff(ym * 0.70710678118f));
        }
        ((float4*)(y_s + rloc * 512))[lane] = o0;
        ((float4*)(y_s + rloc * 512))[lane + 64] = o1;
    }
    __syncthreads();
    int o = t & 63, rg = t >> 6;
    float a0 = 0.f, a1 = 0.f;
#pragma unroll 4
    for (int c = 0; c < 512; c++) {
        float wv_ = Wout[c * 64 + o];
        a0 = fmaf(y_s[(rg * 2) * 512 + c], wv_, a0);
        a1 = fmaf(y_s[(rg * 2 + 1) * 512 + c], wv_, a1);
    }
    float bo = bout[o];
    out[(size_t)(r0 + rg * 2) * 64 + o] = a0 + bo;
    out[(size_t)(r0 + rg * 2 + 1) * 64 + o] = a1 + bo;
}

extern "C" void kernel_launch(void* const* d_in, const int* in_sizes, int n_in,
                              void* d_out, int out_size, void* d_ws, size_t ws_size,
                              hipStream_t stream) {
    const float* x = (const float*)d_in[0];
    const float* Wqkv = (const float*)d_in[1];
    const float* bqkv = (const float*)d_in[2];
    const float* lng = (const float*)d_in[3];
    const float* lnb = (const float*)d_in[4];
    const float* Wout = (const float*)d_in[5];
    const float* bout = (const float*)d_in[6];
    float* out = (float*)d_out;

    float* ws = (float*)d_ws;
    size_t off = 0;
    float* sq = ws + off;    off += (size_t)B * N;
    float* scal = ws + off;  off += 16;
    float* spa = ws + off;   off += (size_t)N * N;            // 1M
    float* wbuf = ws + off;  off += (size_t)B * N * N;        // 4M (holds d2)
    float* aout = ws + off;  off += (size_t)B * N * INNER;    // 2M
    short* sbase = (short*)(ws + off);
    size_t soff = 0;
    short* qeh = sbase + soff; soff += (size_t)BHND;
    short* qel = sbase + soff; soff += (size_t)BHND;
    short* keh = sbase + soff; soff += (size_t)BHND;
    short* vT  = sbase + soff; soff += (size_t)BHND;
    short* Mb  = sbase + soff; soff += (size_t)B * N * N;     // 4M shorts
    short* xh  = sbase + soff; soff += (size_t)B * N * D;
    short* xl  = sbase + soff; soff += (size_t)B * N * D;
    short* Wh  = sbase + soff; soff += (size_t)D * C3;
    short* Wl  = sbase + soff; soff += (size_t)D * C3;

    // spa sigma/mu on host (input-independent)
    double ssum = 0.0;
    const double cnt = (double)N * (double)N;
    for (int dx = -15; dx <= 15; dx++)
        for (int dy = -15; dy <= 15; dy++)
            for (int dz = -3; dz <= 3; dz++) {
                double c = (double)(16 - abs(dx)) * (double)(16 - abs(dy)) * (double)(4 - abs(dz));
                double d2 = (double)(dx * dx + dy * dy + dz * dz);
                ssum += c * sqrt(d2);
            }
    double sigma = ssum / cnt;
    double inv2s2 = 1.0 / (2.0 * sigma * sigma);
    double wsum = 0.0;
    for (int dx = -15; dx <= 15; dx++)
        for (int dy = -15; dy <= 15; dy++)
            for (int dz = -3; dz <= 3; dz++) {
                double c = (double)(16 - abs(dx)) * (double)(16 - abs(dy)) * (double)(4 - abs(dz));
                double d2 = (double)(dx * dx + dy * dy + dz * dz);
                wsum += c * exp(-d2 * inv2s2);
            }
    double mu = wsum / cnt;

    k_prep<<<2072, 256, 0, stream>>>(x, Wqkv, xh, xl, sq, Wh, Wl, spa, (float)inv2s2, (float)mu, scal);
    k_gemm<<<1280, 256, 0, stream>>>(xh, xl, Wh, Wl, bqkv, sq, qeh, qel, keh, vT, wbuf, scal);
    k_wsum<<<2048, 256, 0, stream>>>(wbuf, scal, scal + 1);
    k_mask<<<2048, 256, 0, stream>>>(wbuf, spa, scal, Mb);
    k_attn<<<512, 256, 0, stream>>>(qeh, qel, keh, vT, Mb, aout);
    k_out<<<512, 256, 0, stream>>>(aout, lng, lnb, Wout, bout, out);
}

// Round 14
// 213.502 us; speedup vs baseline: 1.0930x; 1.0930x over previous
//
#include <hip/hip_runtime.h>
#include <math.h>
#include <stdlib.h>

#define B 4
#define N 1024
#define D 64
#define H 8
#define DH 64
#define INNER 512
#define C3 1536
#define BHN 32768        // B*H*N
#define BHND 2097152     // B*H*N*DH

typedef __attribute__((ext_vector_type(8))) short bf16x8;
typedef __attribute__((ext_vector_type(4))) float f32x4;

__device__ inline short f2bf(float f) {
    unsigned u = __builtin_bit_cast(unsigned, f);
    unsigned r = (u + 0x7FFFu + ((u >> 16) & 1u)) >> 16;
    return (short)r;
}
__device__ inline float bf2f(short s) {
    return __builtin_bit_cast(float, ((unsigned)(unsigned short)s) << 16);
}

// ---------------- prep: x->xh/xl+sq | Wqkv->Wh/Wl transposed | scal zero ----------------
__global__ __launch_bounds__(256) void k_prep(const float* __restrict__ x, const float* __restrict__ Wqkv,
                                              short* __restrict__ xh, short* __restrict__ xl,
                                              float* __restrict__ sq,
                                              short* __restrict__ Wh, short* __restrict__ Wl,
                                              float* __restrict__ scal) {
    __shared__ float lds[64 * 65];
    int t = threadIdx.x;
    int bb = blockIdx.x;
    if (bb < 1024) {
        if (bb == 0 && t < 16) scal[t] = 0.f;
        int i = bb * 4 + (t >> 6), d = t & 63;
        float v = x[i * 64 + d];
        short hs = f2bf(v);
        xh[i * 64 + d] = hs;
        xl[i * 64 + d] = f2bf(v - bf2f(hs));
        float s = v * v;
#pragma unroll
        for (int m = 32; m; m >>= 1) s += __shfl_xor(s, m, 64);
        if (d == 0) sq[i] = s;
    } else {
        int c0 = (bb - 1024) * 64;
#pragma unroll
        for (int it = 0; it < 16; it++) {
            int d = it * 4 + (t >> 6), cl = t & 63;
            lds[cl * 65 + d] = Wqkv[d * C3 + c0 + cl];
        }
        __syncthreads();
#pragma unroll
        for (int it = 0; it < 16; it++) {
            int cl = it * 4 + (t >> 6), d = t & 63;
            float v = lds[cl * 65 + d];
            short hs = f2bf(v);
            Wh[(c0 + cl) * 64 + d] = hs;
            Wl[(c0 + cl) * 64 + d] = f2bf(v - bf2f(hs));
        }
    }
}

// ---------------- fused GEMM kernel: qkv-proj (blocks <768) | gram (blocks >=768) ----------------
__global__ __launch_bounds__(256) void k_gemm(
    const short* __restrict__ xh, const short* __restrict__ xl,
    const short* __restrict__ Wh, const short* __restrict__ Wl,
    const float* __restrict__ bqkv, const float* __restrict__ sq,
    short* __restrict__ qeh, short* __restrict__ qel,
    short* __restrict__ keh,
    short* __restrict__ vT, float* __restrict__ w, float* __restrict__ d_sig) {
    __shared__ short vt_lds[128 * 66];
    __shared__ float red[4];
    int t = threadIdx.x;
    int wv = t >> 6, lane = t & 63, l4 = lane & 15, g = lane >> 4;
    const bf16x8* xh8 = (const bf16x8*)xh;
    const bf16x8* xl8 = (const bf16x8*)xl;

    if (blockIdx.x < 768) {
        int i0 = (blockIdx.x & 63) * 64;
        int c0 = (blockIdx.x >> 6) * 128;
        int irow = i0 + wv * 16;
        const bf16x8* Wh8 = (const bf16x8*)Wh;
        const bf16x8* Wl8 = (const bf16x8*)Wl;
        int abase = (irow + l4) * 8 + g;
        bf16x8 ah[2], al[2];
        ah[0] = xh8[abase];
        ah[1] = xh8[abase + 4];
        al[0] = xl8[abase];
        al[1] = xl8[abase + 4];
        f32x4 acc[8];
#pragma unroll
        for (int ct = 0; ct < 8; ct++) {
            int c = c0 + 16 * ct + l4;
            int bbase = c * 8 + g;
            bf16x8 bh0 = Wh8[bbase], bh1 = Wh8[bbase + 4];
            bf16x8 bl0 = Wl8[bbase], bl1 = Wl8[bbase + 4];
            f32x4 a = f32x4{0.f, 0.f, 0.f, 0.f};
            a = __builtin_amdgcn_mfma_f32_16x16x32_bf16(ah[0], bh0, a, 0, 0, 0);
            a = __builtin_amdgcn_mfma_f32_16x16x32_bf16(ah[1], bh1, a, 0, 0, 0);
            a = __builtin_amdgcn_mfma_f32_16x16x32_bf16(al[0], bh0, a, 0, 0, 0);
            a = __builtin_amdgcn_mfma_f32_16x16x32_bf16(al[1], bh1, a, 0, 0, 0);
            a = __builtin_amdgcn_mfma_f32_16x16x32_bf16(ah[0], bl0, a, 0, 0, 0);
            a = __builtin_amdgcn_mfma_f32_16x16x32_bf16(ah[1], bl1, a, 0, 0, 0);
            acc[ct] = a;
        }
        int seg = c0 >> 9;
#pragma unroll
        for (int ct = 0; ct < 8; ct++) {
            int c = c0 + 16 * ct + l4;
            float bias = bqkv[c];
            int cc = c & 511, hh = cc >> 6, dh = cc & 63;
#pragma unroll
            for (int r = 0; r < 4; r++) {
                int i_e = irow + 4 * g + r;
                int b = i_e >> 10, i = i_e & 1023;
                float val = acc[ct][r] + bias;
                if (seg < 2) {
                    float a_ = val > 0.f ? val + 1.f : __expf(val);
                    short hs = f2bf(a_);
                    int off = ((b * H + hh) * N + i) * 64 + dh;
                    if (seg == 0) {
                        qeh[off] = hs;
                        qel[off] = f2bf(a_ - bf2f(hs));
                    } else {
                        keh[off] = hs;
                    }
                } else {
                    vt_lds[(16 * ct + l4) * 66 + (wv * 16 + 4 * g + r)] = f2bf(val);
                }
            }
        }
        if (seg == 2) {
            __syncthreads();
            int b = i0 >> 10, ib = i0 & 1023;
#pragma unroll
            for (int it = 0; it < 4; it++) {
                int idx = t + 256 * it;
                int cl = idx >> 3, i8 = idx & 7;
                short tmp[8];
#pragma unroll
                for (int r8 = 0; r8 < 8; r8++) tmp[r8] = vt_lds[cl * 66 + i8 * 8 + r8];
                int cc = (c0 + cl) & 511, hh = cc >> 6, dh = cc & 63;
                ((bf16x8*)vT)[((b * H + hh) * 64 + dh) * (N / 8) + (ib >> 3) + i8] = *(bf16x8*)tmp;
            }
        }
    } else {
        int q = blockIdx.x - 768;
        int i0 = (q & 15) * 64, j0 = ((q >> 4) & 7) * 128, b = q >> 7;
        int irow = i0 + wv * 16;
        int abase = (b * N + irow + l4) * 8 + g;
        bf16x8 ah[2], al[2];
        ah[0] = xh8[abase];
        ah[1] = xh8[abase + 4];
        al[0] = xl8[abase];
        al[1] = xl8[abase + 4];
        f32x4 acc[8];
#pragma unroll
        for (int ct = 0; ct < 8; ct++) {
            int j = j0 + 16 * ct + l4;
            int bbase = (b * N + j) * 8 + g;
            bf16x8 bh0 = xh8[bbase], bh1 = xh8[bbase + 4];
            bf16x8 bl0 = xl8[bbase], bl1 = xl8[bbase + 4];
            f32x4 a = f32x4{0.f, 0.f, 0.f, 0.f};
            a = __builtin_amdgcn_mfma_f32_16x16x32_bf16(ah[0], bh0, a, 0, 0, 0);
            a = __builtin_amdgcn_mfma_f32_16x16x32_bf16(ah[1], bh1, a, 0, 0, 0);
            a = __builtin_amdgcn_mfma_f32_16x16x32_bf16(al[0], bh0, a, 0, 0, 0);
            a = __builtin_amdgcn_mfma_f32_16x16x32_bf16(al[1], bh1, a, 0, 0, 0);
            a = __builtin_amdgcn_mfma_f32_16x16x32_bf16(ah[0], bl0, a, 0, 0, 0);
            a = __builtin_amdgcn_mfma_f32_16x16x32_bf16(ah[1], bl1, a, 0, 0, 0);
            acc[ct] = a;
        }
        float sqi[4];
#pragma unroll
        for (int r = 0; r < 4; r++) sqi[r] = sq[b * N + irow + 4 * g + r];
        float part = 0.f;
#pragma unroll
        for (int ct = 0; ct < 8; ct++) {
            int j = j0 + 16 * ct + l4;
            float sqj = sq[b * N + j];
#pragma unroll
            for (int r = 0; r < 4; r++) {
                float d2 = sqi[r] + sqj - 2.f * acc[ct][r];
                d2 = fmaxf(d2, 0.f);
                w[((size_t)b * N + irow + 4 * g + r) * N + j] = d2;
                part += (d2 > 1e-12f) ? sqrtf(d2) : 0.f;
            }
        }
#pragma unroll
        for (int m = 32; m; m >>= 1) part += __shfl_xor(part, m, 64);
        if (lane == 0) red[wv] = part;
        __syncthreads();
        if (t == 0) atomicAdd(d_sig, red[0] + red[1] + red[2] + red[3]);
    }
}

// ---------------- wsum: read-only reduction of exp(-d2/(2 sigma^2)) ----------------
__global__ __launch_bounds__(256) void k_wsum(const float* __restrict__ w, const float* __restrict__ d_sig,
                                              float* __restrict__ d_wsum) {
    __shared__ float red[4];
    float sigma = d_sig[0] * (1.f / 4194304.f);
    float inv = 1.f / (2.f * sigma * sigma);
    float s = 0.f;
    for (int idx = blockIdx.x * 256 + threadIdx.x; idx < 1048576; idx += 256 * 2048) {
        float4 v = ((const float4*)w)[idx];
        s += __expf(-v.x * inv) + __expf(-v.y * inv) + __expf(-v.z * inv) + __expf(-v.w * inv);
    }
#pragma unroll
    for (int m = 32; m; m >>= 1) s += __shfl_xor(s, m, 64);
    if ((threadIdx.x & 63) == 0) red[threadIdx.x >> 6] = s;
    __syncthreads();
    if (threadIdx.x == 0) atomicAdd(d_wsum, red[0] + red[1] + red[2] + red[3]);
}

// ---------------- mask: Mb = thresh(exp(-d2 inv))*spa(i,j)*0.125 in bf16 (spa inline) ----------------
__global__ __launch_bounds__(256) void k_mask(const float* __restrict__ w, const float* __restrict__ scal,
                                              float spa_inv2s2, float spa_mu, short* __restrict__ Mb) {
    float sigma = scal[0] * (1.f / 4194304.f);
    float inv = 1.f / (2.f * sigma * sigma);
    float mu = scal[1] * (1.f / 4194304.f);
    float d2thr = -__logf(mu) / inv;   // w < mu  <=>  d2 > d2thr
    for (int idx = blockIdx.x * 256 + threadIdx.x; idx < 1048576; idx += 256 * 2048) {
        float4 d2v = ((const float4*)w)[idx];
        int i = (idx >> 8) & 1023;
        int j0 = (idx & 255) * 4;
        int ix = i >> 6, iy = (i >> 2) & 15, iz = i & 3;
        short tmp[4];
        float* dp = (float*)&d2v;
#pragma unroll
        for (int e = 0; e < 4; e++) {
            int j = j0 + e;
            int jx = j >> 6, jy = (j >> 2) & 15, jz = j & 3;
            float gd2 = (float)((ix - jx) * (ix - jx) + (iy - jy) * (iy - jy) + (iz - jz) * (iz - jz));
            float sp = __expf(-gd2 * spa_inv2s2);
            sp = (sp < spa_mu) ? 0.f : sp;
            float m = (dp[e] > d2thr) ? 0.f : __expf(-dp[e] * inv) * sp * 0.125f;
            tmp[e] = f2bf(m);
        }
        *(uint2*)(Mb + (size_t)idx * 4) = *(uint2*)tmp;
    }
}

// ---------------- attention: MFMA flash, bf16 mask, direct staging, XCD-grouped ----------------
__global__ __launch_bounds__(256) void k_attn(
    const short* __restrict__ qeh, const short* __restrict__ qel,
    const short* __restrict__ keh,
    const short* __restrict__ vT, const short* __restrict__ Mb,
    float* __restrict__ aout) {
    __shared__ short Kh[64 * 64];
    __shared__ short Vt[64 * 64];
    __shared__ short P[4][16 * 64];
    int t = threadIdx.x;
    int wv = t >> 6, lane = t & 63, l4 = lane & 15, g = lane >> 4;
    // XCD-grouped decode: all blocks of head h land on XCD h (L2 reuse of K/V)
    int bid = blockIdx.x;
    int h = bid & 7;
    int iblk = (bid >> 3) & 15;
    int b = bid >> 7;
    int i0 = iblk * 64;
    int bh = b * H + h;
    int irow = i0 + wv * 16;

    bf16x8 qh[2], ql[2];
    {
        const bf16x8* qh8 = (const bf16x8*)qeh;
        const bf16x8* ql8 = (const bf16x8*)qel;
        int base = (bh * N + irow + l4) * 8 + g;
#pragma unroll
        for (int mk = 0; mk < 2; mk++) {
            qh[mk] = qh8[base + 4 * mk];
            ql[mk] = ql8[base + 4 * mk];
        }
    }
    f32x4 O[4];
#pragma unroll
    for (int dt = 0; dt < 4; dt++) O[dt] = f32x4{0.f, 0.f, 0.f, 0.f};
    float m_r[4] = {-INFINITY, -INFINITY, -INFINITY, -INFINITY};
    float l_r[4] = {0.f, 0.f, 0.f, 0.f};

    const bf16x8* Kh8 = (const bf16x8*)Kh;
    const bf16x8* Vt8 = (const bf16x8*)Vt;

    for (int tile = 0; tile < 16; ++tile) {
        int j0 = tile * 64;
        __syncthreads();
        {
            const bf16x8* kh8 = (const bf16x8*)keh;
            const bf16x8* v8 = (const bf16x8*)vT;
            bf16x8* KhW = (bf16x8*)Kh;
            bf16x8* VtW = (bf16x8*)Vt;
#pragma unroll
            for (int rep = 0; rep < 2; rep++) {
                int c = t + 256 * rep;
                int j = c >> 3, s = c & 7;
                KhW[j * 8 + (s ^ (j & 7))] = kh8[(bh * N + j0 + j) * 8 + s];
                VtW[j * 8 + (s ^ (j & 7))] = v8[(bh * 64 + j) * (N / 8) + (j0 >> 3) + s];
            }
        }
        __syncthreads();
        f32x4 sc[4];
        __builtin_amdgcn_s_setprio(1);
#pragma unroll
        for (int ct = 0; ct < 4; ct++) {
            int j = 16 * ct + l4;
            int sw = j & 7;
            bf16x8 kh0 = Kh8[j * 8 + ((g) ^ sw)];
            bf16x8 kh1 = Kh8[j * 8 + ((4 + g) ^ sw)];
            f32x4 a = f32x4{0.f, 0.f, 0.f, 0.f};
            a = __builtin_amdgcn_mfma_f32_16x16x32_bf16(qh[0], kh0, a, 0, 0, 0);
            a = __builtin_amdgcn_mfma_f32_16x16x32_bf16(qh[1], kh1, a, 0, 0, 0);
            a = __builtin_amdgcn_mfma_f32_16x16x32_bf16(ql[0], kh0, a, 0, 0, 0);
            a = __builtin_amdgcn_mfma_f32_16x16x32_bf16(ql[1], kh1, a, 0, 0, 0);
            sc[ct] = a;
        }
        __builtin_amdgcn_s_setprio(0);
        float p[4][4];
        float fr[4];
#pragma unroll
        for (int r = 0; r < 4; r++) {
            int i = irow + 4 * g + r;
            const short* Mrow = Mb + ((size_t)b * N + i) * N + j0;
            float mx = -INFINITY;
#pragma unroll
            for (int ct = 0; ct < 4; ct++) {
                float mval = bf2f(Mrow[16 * ct + l4]);
                float val = sc[ct][r] * mval;
                p[ct][r] = val;
                mx = fmaxf(mx, val);
            }
#pragma unroll
            for (int msk = 1; msk < 16; msk <<= 1) mx = fmaxf(mx, __shfl_xor(mx, msk, 64));
            float mo = m_r[r];
            float mn = fmaxf(mo, mx);
            float f = __expf(mo - mn);
            float s = 0.f;
#pragma unroll
            for (int ct = 0; ct < 4; ct++) {
                float e = __expf(p[ct][r] - mn);
                p[ct][r] = e;
                s += e;
            }
#pragma unroll
            for (int msk = 1; msk < 16; msk <<= 1) s += __shfl_xor(s, msk, 64);
            l_r[r] = l_r[r] * f + s;
            m_r[r] = mn;
            fr[r] = f;
        }
#pragma unroll
        for (int dt = 0; dt < 4; dt++) {
            O[dt][0] *= fr[0];
            O[dt][1] *= fr[1];
            O[dt][2] *= fr[2];
            O[dt][3] *= fr[3];
        }
        short* Pw = P[wv];
#pragma unroll
        for (int ct = 0; ct < 4; ct++) {
#pragma unroll
            for (int r = 0; r < 4; r++) {
                int row = 4 * g + r;
                int slot = ((l4 >> 3) + 2 * ct) ^ (row & 7);
                Pw[row * 64 + slot * 8 + (l4 & 7)] = f2bf(p[ct][r]);
            }
        }
        const bf16x8* Pr = (const bf16x8*)P[wv];
        __builtin_amdgcn_s_setprio(1);
#pragma unroll
        for (int ks = 0; ks < 2; ks++) {
            bf16x8 pa = Pr[l4 * 8 + ((g + 4 * ks) ^ (l4 & 7))];
#pragma unroll
            for (int dt = 0; dt < 4; dt++) {
                int d = l4 + 16 * dt;
                bf16x8 bv = Vt8[d * 8 + ((g + 4 * ks) ^ (d & 7))];
                O[dt] = __builtin_amdgcn_mfma_f32_16x16x32_bf16(pa, bv, O[dt], 0, 0, 0);
            }
        }
        __builtin_amdgcn_s_setprio(0);
    }
#pragma unroll
    for (int dt = 0; dt < 4; dt++) {
#pragma unroll
        for (int r = 0; r < 4; r++) {
            int i = irow + 4 * g + r;
            aout[((size_t)b * N + i) * INNER + h * 64 + l4 + 16 * dt] = O[dt][r] / l_r[r];
        }
    }
}

// ---------------- LN + GELU + out proj (8 rows/block) ----------------
__global__ __launch_bounds__(256) void k_out(const float* __restrict__ aout, const float* __restrict__ g,
                                             const float* __restrict__ be, const float* __restrict__ Wout,
                                             const float* __restrict__ bout, float* __restrict__ out) {
    __shared__ float y_s[8 * 512];
    int t = threadIdx.x;
    int wv = t >> 6, lane = t & 63;
    int r0 = blockIdx.x * 8;
#pragma unroll
    for (int rr = 0; rr < 2; rr++) {
        int rloc = wv * 2 + rr;
        const float* rp = aout + (size_t)(r0 + rloc) * 512;
        float4 v0 = ((const float4*)rp)[lane];
        float4 v1 = ((const float4*)rp)[lane + 64];
        float s1 = v0.x + v0.y + v0.z + v0.w + v1.x + v1.y + v1.z + v1.w;
        float s2 = v0.x * v0.x + v0.y * v0.y + v0.z * v0.z + v0.w * v0.w +
                   v1.x * v1.x + v1.y * v1.y + v1.z * v1.z + v1.w * v1.w;
#pragma unroll
        for (int m = 32; m; m >>= 1) {
            s1 += __shfl_xor(s1, m, 64);
            s2 += __shfl_xor(s2, m, 64);
        }
        float mean = s1 * (1.f / 512.f);
        float var = s2 * (1.f / 512.f) - mean * mean;
        float rstd = rsqrtf(var + 1e-5f);
        int c0 = 4 * lane, c1 = 4 * lane + 256;
        float4 o0, o1;
#pragma unroll
        for (int e = 0; e < 4; e++) {
            float yn = g[c0 + e] * (((float*)&v0)[e] - mean) * rstd + be[c0 + e];
            ((float*)&o0)[e] = 0.5f * yn * (1.f + erff(yn * 0.70710678118f));
            float ym = g[c1 + e] * (((float*)&v1)[e] - mean) * rstd + be[c1 + e];
            ((float*)&o1)[e] = 0.5f * ym * (1.f + erff(ym * 0.70710678118f));
        }
        ((float4*)(y_s + rloc * 512))[lane] = o0;
        ((float4*)(y_s + rloc * 512))[lane + 64] = o1;
    }
    __syncthreads();
    int o = t & 63, rg = t >> 6;
    float a0 = 0.f, a1 = 0.f;
#pragma unroll 4
    for (int c = 0; c < 512; c++) {
        float wv_ = Wout[c * 64 + o];
        a0 = fmaf(y_s[(rg * 2) * 512 + c], wv_, a0);
        a1 = fmaf(y_s[(rg * 2 + 1) * 512 + c], wv_, a1);
    }
    float bo = bout[o];
    out[(size_t)(r0 + rg * 2) * 64 + o] = a0 + bo;
    out[(size_t)(r0 + rg * 2 + 1) * 64 + o] = a1 + bo;
}

extern "C" void kernel_launch(void* const* d_in, const int* in_sizes, int n_in,
                              void* d_out, int out_size, void* d_ws, size_t ws_size,
                              hipStream_t stream) {
    const float* x = (const float*)d_in[0];
    const float* Wqkv = (const float*)d_in[1];
    const float* bqkv = (const float*)d_in[2];
    const float* lng = (const float*)d_in[3];
    const float* lnb = (const float*)d_in[4];
    const float* Wout = (const float*)d_in[5];
    const float* bout = (const float*)d_in[6];
    float* out = (float*)d_out;

    float* ws = (float*)d_ws;
    size_t off = 0;
    float* sq = ws + off;    off += (size_t)B * N;
    float* scal = ws + off;  off += 16;
    float* wbuf = ws + off;  off += (size_t)B * N * N;        // 4M (holds d2)
    float* aout = ws + off;  off += (size_t)B * N * INNER;    // 2M
    short* sbase = (short*)(ws + off);
    size_t soff = 0;
    short* qeh = sbase + soff; soff += (size_t)BHND;
    short* qel = sbase + soff; soff += (size_t)BHND;
    short* keh = sbase + soff; soff += (size_t)BHND;
    short* vT  = sbase + soff; soff += (size_t)BHND;
    short* Mb  = sbase + soff; soff += (size_t)B * N * N;     // 4M shorts
    short* xh  = sbase + soff; soff += (size_t)B * N * D;
    short* xl  = sbase + soff; soff += (size_t)B * N * D;
    short* Wh  = sbase + soff; soff += (size_t)D * C3;
    short* Wl  = sbase + soff; soff += (size_t)D * C3;

    // spa sigma/mu on host (input-independent)
    double ssum = 0.0;
    const double cnt = (double)N * (double)N;
    for (int dx = -15; dx <= 15; dx++)
        for (int dy = -15; dy <= 15; dy++)
            for (int dz = -3; dz <= 3; dz++) {
                double c = (double)(16 - abs(dx)) * (double)(16 - abs(dy)) * (double)(4 - abs(dz));
                double d2 = (double)(dx * dx + dy * dy + dz * dz);
                ssum += c * sqrt(d2);
            }
    double sigma = ssum / cnt;
    double inv2s2 = 1.0 / (2.0 * sigma * sigma);
    double wsum = 0.0;
    for (int dx = -15; dx <= 15; dx++)
        for (int dy = -15; dy <= 15; dy++)
            for (int dz = -3; dz <= 3; dz++) {
                double c = (double)(16 - abs(dx)) * (double)(16 - abs(dy)) * (double)(4 - abs(dz));
                double d2 = (double)(dx * dx + dy * dy + dz * dz);
                wsum += c * exp(-d2 * inv2s2);
            }
    double mu = wsum / cnt;

    k_prep<<<1048, 256, 0, stream>>>(x, Wqkv, xh, xl, sq, Wh, Wl, scal);
    k_gemm<<<1280, 256, 0, stream>>>(xh, xl, Wh, Wl, bqkv, sq, qeh, qel, keh, vT, wbuf, scal);
    k_wsum<<<2048, 256, 0, stream>>>(wbuf, scal, scal + 1);
    k_mask<<<2048, 256, 0, stream>>>(wbuf, scal, (float)inv2s2, (float)mu, Mb);
    k_attn<<<512, 256, 0, stream>>>(qeh, qel, keh, vT, Mb, aout);
    k_out<<<512, 256, 0, stream>>>(aout, lng, lnb, Wout, bout, out);
}